// Round 5
// baseline (468.773 us; speedup 1.0000x reference)
//
#include <hip/hip_runtime.h>
#include <math.h>

#define N   512
#define CS  384
#define CZ  128
#define H   12
#define C   16
#define P   4
#define PV  8
#define NB  64
#define KSP 528   // K-slice for k_out (2112/4)
#define QKD 28    // 16 (q·k) + 12 (qg·kg) fused dot length
#define QPAD 68   // d-major LDS row stride (k_qkpt)
#define APAD 516  // attn LDS row stride (516%32=4 -> h-stride mostly distinct banks)

// workspace offsets (in floats)
#define OFF_Q    0         // 512*192
#define OFF_K    98304     // 512*192
#define OFF_V    196608    // 512*192
#define OFF_QP   294912    // 512*144
#define OFF_KP   368640    // 512*144
#define OFF_VP   442368    // 512*288
#define OFF_QG   589824    // 512*144
#define OFF_KG   663552    // 512*144
#define OFF_VG   737280    // 512*288
#define OFF_QSQ  884736    // 512*12
#define OFF_KSQ  890880    // 512*12
#define OFF_LOG  897024    // 512*12*512  (raw logits; softmax stays in LDS)
#define OFF_FEAT 4042752   // 512*2112

// ---------------- Kernel 1: all six projections (streamed GEMM) -----------------
__global__ __launch_bounds__(256) void k_proj(
    const float* __restrict__ s,
    const float* __restrict__ Wq,  const float* __restrict__ bq,
    const float* __restrict__ Wk,  const float* __restrict__ bk,
    const float* __restrict__ Wv,  const float* __restrict__ bv,
    const float* __restrict__ Wqp, const float* __restrict__ bqp,
    const float* __restrict__ Wkp, const float* __restrict__ bkp,
    const float* __restrict__ Wvp, const float* __restrict__ bvp,
    float* __restrict__ ws)
{
    __shared__ float s_s[16*388];
    const int tid = threadIdx.x;
    const int n0  = blockIdx.y * 16;
    const int gc  = blockIdx.x * 64 + (tid & 15) * 4;
    const int nl  = tid >> 4;
    for (int i = tid; i < 16*384; i += 256) {
        int r = i / 384, c = i - r*384;
        s_s[r*388 + c] = s[(n0 + r)*384 + c];
    }
    __syncthreads();
    const float* W; const float* b; float* dst; int width; int lc;
    if      (gc < 192) { W=Wq;  b=bq;  width=192; lc=gc;     dst=ws+OFF_Q;  }
    else if (gc < 384) { W=Wk;  b=bk;  width=192; lc=gc-192; dst=ws+OFF_K;  }
    else if (gc < 576) { W=Wv;  b=bv;  width=192; lc=gc-384; dst=ws+OFF_V;  }
    else if (gc < 720) { W=Wqp; b=bqp; width=144; lc=gc-576; dst=ws+OFF_QP; }
    else if (gc < 864) { W=Wkp; b=bkp; width=144; lc=gc-720; dst=ws+OFF_KP; }
    else               { W=Wvp; b=bvp; width=288; lc=gc-864; dst=ws+OFF_VP; }
    float4 acc = {0.f,0.f,0.f,0.f};
    const float* wp   = W + lc;
    const float* srow = s_s + nl*388;
    #pragma unroll 8
    for (int kk = 0; kk < 384; kk++) {
        float4 w4 = *(const float4*)(wp + (size_t)kk*width);
        float  sv = srow[kk];
        acc.x += sv*w4.x; acc.y += sv*w4.y; acc.z += sv*w4.z; acc.w += sv*w4.w;
    }
    float4 b4 = *(const float4*)(b + lc);
    acc.x += b4.x; acc.y += b4.y; acc.z += b4.z; acc.w += b4.w;
    *(float4*)(dst + (size_t)(n0+nl)*width + lc) = acc;
}

// ---------------- Kernel 2: global frames + q_sq/k_sq -----------------
__global__ __launch_bounds__(192) void k_frames(
    const float* __restrict__ rot, const float* __restrict__ trans,
    float* __restrict__ ws)
{
    int n = blockIdx.x, tid = threadIdx.x;
    __shared__ float R[9], T[3], qg_s[144], kg_s[144];
    if (tid < 9) R[tid] = rot[n*9 + tid];
    if (tid < 3) T[tid] = trans[n*3 + tid];
    __syncthreads();
    if (tid < 48) {
        const float* lp = ws + OFF_QP + n*144 + tid*3;
        float l0=lp[0], l1=lp[1], l2=lp[2];
        float* gp = ws + OFF_QG + n*144 + tid*3;
        for (int i=0;i<3;i++){ float g = R[i*3+0]*l0 + R[i*3+1]*l1 + R[i*3+2]*l2 + T[i]; gp[i]=g; qg_s[tid*3+i]=g; }
    } else if (tid < 96) {
        int u = tid-48;
        const float* lp = ws + OFF_KP + n*144 + u*3;
        float l0=lp[0], l1=lp[1], l2=lp[2];
        float* gp = ws + OFF_KG + n*144 + u*3;
        for (int i=0;i<3;i++){ float g = R[i*3+0]*l0 + R[i*3+1]*l1 + R[i*3+2]*l2 + T[i]; gp[i]=g; kg_s[u*3+i]=g; }
    } else {
        int u = tid-96;
        const float* lp = ws + OFF_VP + n*288 + u*3;
        float l0=lp[0], l1=lp[1], l2=lp[2];
        float* gp = ws + OFF_VG + n*288 + u*3;
        for (int i=0;i<3;i++){ float g = R[i*3+0]*l0 + R[i*3+1]*l1 + R[i*3+2]*l2 + T[i]; gp[i]=g; }
    }
    __syncthreads();
    if (tid < 12) {
        float a=0;
        for (int d=0; d<12; d++){ float x=qg_s[tid*12+d]; a+=x*x; }
        ws[OFF_QSQ + n*12 + tid]=a;
    } else if (tid < 24) {
        int h = tid-12; float a=0;
        for (int d=0; d<12; d++){ float x=kg_s[h*12+d]; a+=x*x; }
        ws[OFF_KSQ + n*12 + h]=a;
    }
}

// ---------------- Kernel 3a: qk + point logits, per-head 64x64 tiles ----------
__global__ __launch_bounds__(256) void k_qkpt(
    const float* __restrict__ head_weights, float* __restrict__ ws)
{
    __shared__ float qs[QKD*QPAD], ks[QKD*QPAD], qa[64], kb[64];
    const int tid = threadIdx.x;
    const int m0 = blockIdx.x * 64, n0 = blockIdx.y * 64, h = blockIdx.z;
    const float hw = head_weights[h];
    for (int idx = tid; idx < 64*16; idx += 256) {
        int r = idx >> 4, c = idx & 15;
        qs[c*QPAD + r] = ws[OFF_Q + (n0+r)*192 + h*16 + c] * 0.25f;
        ks[c*QPAD + r] = ws[OFF_K + (m0+r)*192 + h*16 + c];
    }
    for (int idx = tid; idx < 64*12; idx += 256) {
        int r = idx / 12, c = idx % 12;
        qs[(16+c)*QPAD + r] = ws[OFF_QG + (n0+r)*144 + h*12 + c] * hw;
        ks[(16+c)*QPAD + r] = ws[OFF_KG + (m0+r)*144 + h*12 + c];
    }
    for (int idx = tid; idx < 64; idx += 256) {
        qa[idx] = -0.5f * hw * ws[OFF_QSQ + (n0+idx)*12 + h];
        kb[idx] = -0.5f * hw * ws[OFF_KSQ + (m0+idx)*12 + h];
    }
    __syncthreads();
    const int tx = tid & 15, ty = tid >> 4;
    float acc[4][4] = {{0.f}};
    #pragma unroll 4
    for (int d = 0; d < QKD; d++) {
        float4 a = *(const float4*)(qs + d*QPAD + ty*4);
        float4 b = *(const float4*)(ks + d*QPAD + tx*4);
        const float* ap = &a.x; const float* bp = &b.x;
        #pragma unroll
        for (int i=0;i<4;i++)
            #pragma unroll
            for (int j=0;j<4;j++) acc[i][j] += ap[i]*bp[j];
    }
    #pragma unroll
    for (int i=0;i<4;i++) {
        float ai = qa[ty*4+i];
        float4 r;
        r.x = acc[i][0] + ai + kb[tx*4+0];
        r.y = acc[i][1] + ai + kb[tx*4+1];
        r.z = acc[i][2] + ai + kb[tx*4+2];
        r.w = acc[i][3] + ai + kb[tx*4+3];
        *(float4*)(ws + OFF_LOG + ((size_t)(n0+ty*4+i)*H + h)*N + m0 + tx*4) = r;
    }
}

// ---------------- Kernel 3b: += z@Wb + bb + dist_bias + multiscale -------------
__global__ __launch_bounds__(256) void k_zbias(
    const float* __restrict__ z, const float* __restrict__ trans,
    const float* __restrict__ Wb, const float* __restrict__ bb,
    const float* __restrict__ dist_emb, const float* __restrict__ scale_logits,
    float* __restrict__ ws)
{
    const int n = blockIdx.y;
    const int m = blockIdx.x * 256 + threadIdx.x;
    float dx = trans[n*3+0]-trans[m*3+0];
    float dy = trans[n*3+1]-trans[m*3+1];
    float dz = trans[n*3+2]-trans[m*3+2];
    float pd = sqrtf(dx*dx+dy*dy+dz*dz);
    int bin = (int)ceilf(2.f*pd) - 1;
    bin = bin < 0 ? 0 : (bin > NB-1 ? NB-1 : bin);
    const float4 de0 = *(const float4*)(dist_emb + bin*12);
    const float4 de1 = *(const float4*)(dist_emb + bin*12 + 4);
    const float4 de2 = *(const float4*)(dist_emb + bin*12 + 8);
    float de[12] = {de0.x,de0.y,de0.z,de0.w, de1.x,de1.y,de1.z,de1.w, de2.x,de2.y,de2.z,de2.w};
    float acc[12];
    #pragma unroll
    for (int h=0; h<12; h++) {
        float a = scale_logits[0*H+h], b = scale_logits[1*H+h], c = scale_logits[2*H+h];
        float mx = fmaxf(a, fmaxf(b,c));
        float ea=__expf(a-mx), eb=__expf(b-mx), ec=__expf(c-mx);
        float inv = 1.f/(ea+eb+ec);
        float msc = ec*inv;
        if (pd <= 5.f)       msc += ea*inv;
        else if (pd <= 15.f) msc += eb*inv;
        acc[h] = bb[h] + de[h] + msc;
    }
    const float* zp = z + ((size_t)n*N + m)*CZ;
    #pragma unroll 2
    for (int c4 = 0; c4 < CZ/4; c4++) {
        float4 z4 = *(const float4*)(zp + c4*4);
        const float* zv = &z4.x;
        #pragma unroll
        for (int j=0; j<4; j++)
            #pragma unroll
            for (int h=0; h<12; h++)
                acc[h] += zv[j] * Wb[(c4*4+j)*H + h];
    }
    float* lp = ws + OFF_LOG + (size_t)n*H*N + m;
    #pragma unroll
    for (int h=0; h<12; h++)
        lp[(size_t)h*N] += acc[h];
}

// ---------------- Kernel 4: softmax + attn@{z,v,v_g} fused, wave-specialized ---
// block per n, 512 threads. attn lives only in LDS. z tiled through LDS.
// waves 0-5: pair_feat (thread=(c-quad,h), z from LDS)
// waves 6-7: out_scalar/out_pts (thread = 4-col chunk of V/VG, global float4)
__global__ __launch_bounds__(512) void k_attn(
    const float* __restrict__ z, const float* __restrict__ rot,
    const float* __restrict__ trans, float* __restrict__ ws)
{
    __shared__ float attn_s[H*APAD];   // 24.2 KB
    __shared__ float z_s[16*CZ];       // 8 KB
    __shared__ float og_s[288];
    const int n = blockIdx.x, tid = threadIdx.x;

    // load raw logits (row h at stride APAD)
    const float4* asrc = (const float4*)(ws + OFF_LOG + (size_t)n*H*N);
    for (int i = tid; i < H*(N/4); i += 512) {
        int h = i >> 7, q = i & 127;
        *(float4*)(attn_s + h*APAD + q*4) = asrc[h*128 + q];
    }
    __syncthreads();

    // softmax: one wave per row
    const int lane = tid & 63;
    {
        const int wave = tid >> 6;
        for (int h = wave; h < H; h += 8) {
            float* row = attn_s + h*APAD;
            float v[8];
            float mx = -1e30f;
            #pragma unroll
            for (int j=0;j<8;j++){ v[j]=row[lane + j*64]; mx = fmaxf(mx, v[j]); }
            #pragma unroll
            for (int off=32; off>0; off>>=1) mx = fmaxf(mx, __shfl_xor(mx, off, 64));
            float sum = 0.f;
            #pragma unroll
            for (int j=0;j<8;j++){ v[j]=__expf(v[j]-mx); sum += v[j]; }
            #pragma unroll
            for (int off=32; off>0; off>>=1) sum += __shfl_xor(sum, off, 64);
            float inv = 1.f/sum;
            #pragma unroll
            for (int j=0;j<8;j++) row[lane + j*64] = v[j]*inv;
        }
    }

    // per-thread setup
    float4 acc = {0.f,0.f,0.f,0.f};
    int hB = 0, cq4 = 0;                 // phase B params
    const float* aptr = 0;               // phase A: V/VG base
    int astride = 0, ah = 0, col4 = 0; bool aIsV = false, aActive = false;
    if (tid < 384) {
        cq4 = (tid & 31) * 4;
        hB  = tid >> 5;
    } else {
        int t = tid - 384;               // 0..127, active t<120
        col4 = t * 4;
        aActive = (col4 < 480);
        if (aActive) {
            if (col4 < 192) { aIsV = true;  ah = col4 >> 4;        aptr = ws + OFF_V  + col4;       astride = 192; }
            else            { aIsV = false; ah = (col4-192) / 24;  aptr = ws + OFF_VG + (col4-192); astride = 288; }
        }
    }
    const float* zp = z + (size_t)n*N*CZ;

    // m-tile loop: 32 tiles of 16 rows
    for (int t0 = 0; t0 < N; t0 += 16) {
        __syncthreads();                 // z_s safe to overwrite
        {
            int row = tid >> 5, c4 = (tid & 31) * 4;
            *(float4*)(z_s + row*CZ + c4) =
                *(const float4*)(zp + (size_t)(t0 + row)*CZ + c4);
        }
        __syncthreads();
        if (tid < 384) {
            const float* arow = attn_s + hB*APAD + t0;
            #pragma unroll
            for (int ml = 0; ml < 16; ml++) {
                float a = arow[ml];
                float4 z4 = *(const float4*)(z_s + ml*CZ + cq4);
                acc.x += a*z4.x; acc.y += a*z4.y; acc.z += a*z4.z; acc.w += a*z4.w;
            }
        } else if (aActive) {
            const float* arow = attn_s + ah*APAD + t0;
            const float* vp = aptr + (size_t)t0*astride;
            #pragma unroll
            for (int ml = 0; ml < 16; ml++) {
                float a = arow[ml];
                float4 v4 = *(const float4*)(vp + (size_t)ml*astride);
                acc.x += a*v4.x; acc.y += a*v4.y; acc.z += a*v4.z; acc.w += a*v4.w;
            }
        }
    }

    // stores
    if (tid < 384) {
        *(float4*)(ws + OFF_FEAT + (size_t)n*2112 + hB*176 + 48 + cq4) = acc;
    } else if (aActive) {
        if (aIsV) {
            *(float4*)(ws + OFF_FEAT + (size_t)n*2112 + ah*176 + (col4 & 15)) = acc;
        } else {
            *(float4*)(og_s + (col4 - 192)) = acc;
        }
    }
    __syncthreads();

    // epilogue: rotate to local frame + norms
    if (tid < 96) {
        const int h = tid >> 3, p = tid & 7;
        float g0 = og_s[h*24 + p*3 + 0] - trans[n*3+0];
        float g1 = og_s[h*24 + p*3 + 1] - trans[n*3+1];
        float g2 = og_s[h*24 + p*3 + 2] - trans[n*3+2];
        const float* R = rot + n*9;
        float* fdst = ws + OFF_FEAT + (size_t)n*2112 + h*176;
        float nsq = 0.f;
        #pragma unroll
        for (int i=0;i<3;i++){
            float l = R[0*3+i]*g0 + R[1*3+i]*g1 + R[2*3+i]*g2;   // R^T
            fdst[16 + p*3 + i] = l;
            nsq += l*l;
        }
        fdst[40 + p] = sqrtf(nsq);
    }
}

// ---------------- Kernel 5a: init out with bias -----------------
__global__ __launch_bounds__(384) void k_bias(
    const float* __restrict__ bout, float* __restrict__ out)
{
    out[(size_t)blockIdx.x*CS + threadIdx.x] = bout[threadIdx.x];
}

// ---------------- Kernel 5b: output GEMM, K split 4 ways, atomicAdd ---------
__global__ __launch_bounds__(256) void k_out(
    const float* __restrict__ Wout, const float* __restrict__ ws,
    float* __restrict__ out)
{
    __shared__ float f_s[16*KSP];
    const int tid = threadIdx.x;
    const int n0  = blockIdx.y * 16;
    const int k0  = blockIdx.z * KSP;
    const int col = blockIdx.x * 64 + (tid & 15) * 4;
    const int nl  = tid >> 4;
    for (int i = tid; i < 16*KSP; i += 256) {
        int r = i / KSP, c = i - r*KSP;
        f_s[i] = ws[OFF_FEAT + (size_t)(n0 + r)*2112 + k0 + c];
    }
    __syncthreads();
    float4 acc = {0.f,0.f,0.f,0.f};
    const float* wp   = Wout + (size_t)k0*CS + col;
    const float* frow = f_s + nl*KSP;
    #pragma unroll 8
    for (int kk = 0; kk < KSP; kk++) {
        float4 w4 = *(const float4*)(wp + (size_t)kk*CS);
        float  fv = frow[kk];
        acc.x += fv*w4.x; acc.y += fv*w4.y; acc.z += fv*w4.z; acc.w += fv*w4.w;
    }
    float* o = out + (size_t)(n0+nl)*CS + col;
    atomicAdd(o+0, acc.x); atomicAdd(o+1, acc.y);
    atomicAdd(o+2, acc.z); atomicAdd(o+3, acc.w);
}

extern "C" void kernel_launch(void* const* d_in, const int* in_sizes, int n_in,
                              void* d_out, int out_size, void* d_ws, size_t ws_size,
                              hipStream_t stream) {
    const float* s     = (const float*)d_in[0];
    const float* z     = (const float*)d_in[1];
    const float* trans = (const float*)d_in[2];
    const float* rot   = (const float*)d_in[3];
    const float* Wq  = (const float*)d_in[5];  const float* bq  = (const float*)d_in[6];
    const float* Wk  = (const float*)d_in[7];  const float* bk  = (const float*)d_in[8];
    const float* Wv  = (const float*)d_in[9];  const float* bv  = (const float*)d_in[10];
    const float* Wqp = (const float*)d_in[11]; const float* bqp = (const float*)d_in[12];
    const float* Wkp = (const float*)d_in[13]; const float* bkp = (const float*)d_in[14];
    const float* Wvp = (const float*)d_in[15]; const float* bvp = (const float*)d_in[16];
    const float* Wb  = (const float*)d_in[17]; const float* bb  = (const float*)d_in[18];
    const float* dist_emb     = (const float*)d_in[19];
    const float* scale_logits = (const float*)d_in[20];
    const float* head_weights = (const float*)d_in[21];
    const float* Wout = (const float*)d_in[22]; const float* bout = (const float*)d_in[23];
    float* out = (float*)d_out;
    float* ws  = (float*)d_ws;

    k_proj<<<dim3(18, 32), 256, 0, stream>>>(s, Wq,bq, Wk,bk, Wv,bv, Wqp,bqp, Wkp,bkp, Wvp,bvp, ws);
    k_frames<<<N, 192, 0, stream>>>(rot, trans, ws);
    k_qkpt<<<dim3(8, 8, 12), 256, 0, stream>>>(head_weights, ws);
    k_zbias<<<dim3(2, 512), 256, 0, stream>>>(z, trans, Wb, bb, dist_emb, scale_logits, ws);
    k_attn<<<N, 512, 0, stream>>>(z, rot, trans, ws);
    k_bias<<<N, CS, 0, stream>>>(bout, out);
    k_out<<<dim3(6, 32, 4), 256, 0, stream>>>(Wout, ws, out);
}

// Round 6
// 448.195 us; speedup vs baseline: 1.0459x; 1.0459x over previous
//
#include <hip/hip_runtime.h>
#include <math.h>

#define N   512
#define CS  384
#define CZ  128
#define H   12
#define C   16
#define P   4
#define PV  8
#define NB  64
#define KSP 528   // K-slice for k_out (2112/4)
#define QKD 28    // 16 (q·k) + 12 (qg·kg) fused dot length
#define QPAD 68   // d-major LDS row stride (k_qkpt)
#define APAD 516  // attn LDS row stride (byte stride 2064 = 16B-aligned, banks offset by 4)

// workspace offsets (in floats)
#define OFF_Q    0         // 512*192
#define OFF_K    98304     // 512*192
#define OFF_V    196608    // 512*192
#define OFF_QP   294912    // 512*144
#define OFF_KP   368640    // 512*144
#define OFF_VP   442368    // 512*288
#define OFF_QG   589824    // 512*144
#define OFF_KG   663552    // 512*144
#define OFF_VG   737280    // 512*288
#define OFF_QSQ  884736    // 512*12
#define OFF_KSQ  890880    // 512*12
#define OFF_LOG  897024    // 512*12*512  (raw logits; softmax stays in LDS)
#define OFF_FEAT 4042752   // 512*2112

// ---------------- Kernel 1: all six projections (streamed GEMM) -----------------
__global__ __launch_bounds__(256) void k_proj(
    const float* __restrict__ s,
    const float* __restrict__ Wq,  const float* __restrict__ bq,
    const float* __restrict__ Wk,  const float* __restrict__ bk,
    const float* __restrict__ Wv,  const float* __restrict__ bv,
    const float* __restrict__ Wqp, const float* __restrict__ bqp,
    const float* __restrict__ Wkp, const float* __restrict__ bkp,
    const float* __restrict__ Wvp, const float* __restrict__ bvp,
    float* __restrict__ ws)
{
    __shared__ float s_s[16*388];
    const int tid = threadIdx.x;
    const int n0  = blockIdx.y * 16;
    const int gc  = blockIdx.x * 64 + (tid & 15) * 4;
    const int nl  = tid >> 4;
    for (int i = tid; i < 16*384; i += 256) {
        int r = i / 384, c = i - r*384;
        s_s[r*388 + c] = s[(n0 + r)*384 + c];
    }
    __syncthreads();
    const float* W; const float* b; float* dst; int width; int lc;
    if      (gc < 192) { W=Wq;  b=bq;  width=192; lc=gc;     dst=ws+OFF_Q;  }
    else if (gc < 384) { W=Wk;  b=bk;  width=192; lc=gc-192; dst=ws+OFF_K;  }
    else if (gc < 576) { W=Wv;  b=bv;  width=192; lc=gc-384; dst=ws+OFF_V;  }
    else if (gc < 720) { W=Wqp; b=bqp; width=144; lc=gc-576; dst=ws+OFF_QP; }
    else if (gc < 864) { W=Wkp; b=bkp; width=144; lc=gc-720; dst=ws+OFF_KP; }
    else               { W=Wvp; b=bvp; width=288; lc=gc-864; dst=ws+OFF_VP; }
    float4 acc = {0.f,0.f,0.f,0.f};
    const float* wp   = W + lc;
    const float* srow = s_s + nl*388;
    #pragma unroll 8
    for (int kk = 0; kk < 384; kk++) {
        float4 w4 = *(const float4*)(wp + (size_t)kk*width);
        float  sv = srow[kk];
        acc.x += sv*w4.x; acc.y += sv*w4.y; acc.z += sv*w4.z; acc.w += sv*w4.w;
    }
    float4 b4 = *(const float4*)(b + lc);
    acc.x += b4.x; acc.y += b4.y; acc.z += b4.z; acc.w += b4.w;
    *(float4*)(dst + (size_t)(n0+nl)*width + lc) = acc;
}

// ---------------- Kernel 2: global frames + q_sq/k_sq -----------------
__global__ __launch_bounds__(192) void k_frames(
    const float* __restrict__ rot, const float* __restrict__ trans,
    float* __restrict__ ws)
{
    int n = blockIdx.x, tid = threadIdx.x;
    __shared__ float R[9], T[3], qg_s[144], kg_s[144];
    if (tid < 9) R[tid] = rot[n*9 + tid];
    if (tid < 3) T[tid] = trans[n*3 + tid];
    __syncthreads();
    if (tid < 48) {
        const float* lp = ws + OFF_QP + n*144 + tid*3;
        float l0=lp[0], l1=lp[1], l2=lp[2];
        float* gp = ws + OFF_QG + n*144 + tid*3;
        for (int i=0;i<3;i++){ float g = R[i*3+0]*l0 + R[i*3+1]*l1 + R[i*3+2]*l2 + T[i]; gp[i]=g; qg_s[tid*3+i]=g; }
    } else if (tid < 96) {
        int u = tid-48;
        const float* lp = ws + OFF_KP + n*144 + u*3;
        float l0=lp[0], l1=lp[1], l2=lp[2];
        float* gp = ws + OFF_KG + n*144 + u*3;
        for (int i=0;i<3;i++){ float g = R[i*3+0]*l0 + R[i*3+1]*l1 + R[i*3+2]*l2 + T[i]; gp[i]=g; kg_s[u*3+i]=g; }
    } else {
        int u = tid-96;
        const float* lp = ws + OFF_VP + n*288 + u*3;
        float l0=lp[0], l1=lp[1], l2=lp[2];
        float* gp = ws + OFF_VG + n*288 + u*3;
        for (int i=0;i<3;i++){ float g = R[i*3+0]*l0 + R[i*3+1]*l1 + R[i*3+2]*l2 + T[i]; gp[i]=g; }
    }
    __syncthreads();
    if (tid < 12) {
        float a=0;
        for (int d=0; d<12; d++){ float x=qg_s[tid*12+d]; a+=x*x; }
        ws[OFF_QSQ + n*12 + tid]=a;
    } else if (tid < 24) {
        int h = tid-12; float a=0;
        for (int d=0; d<12; d++){ float x=kg_s[h*12+d]; a+=x*x; }
        ws[OFF_KSQ + n*12 + h]=a;
    }
}

// ---------------- Kernel 3a: qk + point logits, per-head 64x64 tiles ----------
__global__ __launch_bounds__(256) void k_qkpt(
    const float* __restrict__ head_weights, float* __restrict__ ws)
{
    __shared__ float qs[QKD*QPAD], ks[QKD*QPAD], qa[64], kb[64];
    const int tid = threadIdx.x;
    const int m0 = blockIdx.x * 64, n0 = blockIdx.y * 64, h = blockIdx.z;
    const float hw = head_weights[h];
    for (int idx = tid; idx < 64*16; idx += 256) {
        int r = idx >> 4, c = idx & 15;
        qs[c*QPAD + r] = ws[OFF_Q + (n0+r)*192 + h*16 + c] * 0.25f;
        ks[c*QPAD + r] = ws[OFF_K + (m0+r)*192 + h*16 + c];
    }
    for (int idx = tid; idx < 64*12; idx += 256) {
        int r = idx / 12, c = idx % 12;
        qs[(16+c)*QPAD + r] = ws[OFF_QG + (n0+r)*144 + h*12 + c] * hw;
        ks[(16+c)*QPAD + r] = ws[OFF_KG + (m0+r)*144 + h*12 + c];
    }
    for (int idx = tid; idx < 64; idx += 256) {
        qa[idx] = -0.5f * hw * ws[OFF_QSQ + (n0+idx)*12 + h];
        kb[idx] = -0.5f * hw * ws[OFF_KSQ + (m0+idx)*12 + h];
    }
    __syncthreads();
    const int tx = tid & 15, ty = tid >> 4;
    float acc[4][4] = {{0.f}};
    #pragma unroll 4
    for (int d = 0; d < QKD; d++) {
        float4 a = *(const float4*)(qs + d*QPAD + ty*4);
        float4 b = *(const float4*)(ks + d*QPAD + tx*4);
        const float* ap = &a.x; const float* bp = &b.x;
        #pragma unroll
        for (int i=0;i<4;i++)
            #pragma unroll
            for (int j=0;j<4;j++) acc[i][j] += ap[i]*bp[j];
    }
    #pragma unroll
    for (int i=0;i<4;i++) {
        float ai = qa[ty*4+i];
        float4 r;
        r.x = acc[i][0] + ai + kb[tx*4+0];
        r.y = acc[i][1] + ai + kb[tx*4+1];
        r.z = acc[i][2] + ai + kb[tx*4+2];
        r.w = acc[i][3] + ai + kb[tx*4+3];
        *(float4*)(ws + OFF_LOG + ((size_t)(n0+ty*4+i)*H + h)*N + m0 + tx*4) = r;
    }
}

// ---------------- Kernel 3b: += z@Wb + bb + dist_bias + multiscale -------------
__global__ __launch_bounds__(256) void k_zbias(
    const float* __restrict__ z, const float* __restrict__ trans,
    const float* __restrict__ Wb, const float* __restrict__ bb,
    const float* __restrict__ dist_emb, const float* __restrict__ scale_logits,
    float* __restrict__ ws)
{
    const int n = blockIdx.y;
    const int m = blockIdx.x * 256 + threadIdx.x;
    float dx = trans[n*3+0]-trans[m*3+0];
    float dy = trans[n*3+1]-trans[m*3+1];
    float dz = trans[n*3+2]-trans[m*3+2];
    float pd = sqrtf(dx*dx+dy*dy+dz*dz);
    int bin = (int)ceilf(2.f*pd) - 1;
    bin = bin < 0 ? 0 : (bin > NB-1 ? NB-1 : bin);
    const float4 de0 = *(const float4*)(dist_emb + bin*12);
    const float4 de1 = *(const float4*)(dist_emb + bin*12 + 4);
    const float4 de2 = *(const float4*)(dist_emb + bin*12 + 8);
    float de[12] = {de0.x,de0.y,de0.z,de0.w, de1.x,de1.y,de1.z,de1.w, de2.x,de2.y,de2.z,de2.w};
    float acc[12];
    #pragma unroll
    for (int h=0; h<12; h++) {
        float a = scale_logits[0*H+h], b = scale_logits[1*H+h], c = scale_logits[2*H+h];
        float mx = fmaxf(a, fmaxf(b,c));
        float ea=__expf(a-mx), eb=__expf(b-mx), ec=__expf(c-mx);
        float inv = 1.f/(ea+eb+ec);
        float msc = ec*inv;
        if (pd <= 5.f)       msc += ea*inv;
        else if (pd <= 15.f) msc += eb*inv;
        acc[h] = bb[h] + de[h] + msc;
    }
    const float* zp = z + ((size_t)n*N + m)*CZ;
    #pragma unroll 2
    for (int c4 = 0; c4 < CZ/4; c4++) {
        float4 z4 = *(const float4*)(zp + c4*4);
        const float* zv = &z4.x;
        #pragma unroll
        for (int j=0; j<4; j++)
            #pragma unroll
            for (int h=0; h<12; h++)
                acc[h] += zv[j] * Wb[(c4*4+j)*H + h];
    }
    float* lp = ws + OFF_LOG + (size_t)n*H*N + m;
    #pragma unroll
    for (int h=0; h<12; h++)
        lp[(size_t)h*N] += acc[h];
}

// ---------------- Kernel 4: softmax + attn@{z,v,v_g} fused -----------------
// block per n, 512 threads. attn lives only in LDS. z read from global (L2-hot).
// waves 0-5: pair_feat, wave w handles h=w and h=w+6 (2 accs/lane);
//            half-wave sub splits m odd/even, merged via shfl_xor(32).
// waves 6-7: out_scalar/out_pts (thread = 4-col chunk of V/VG, global float4)
__global__ __launch_bounds__(512) void k_attn(
    const float* __restrict__ z, const float* __restrict__ rot,
    const float* __restrict__ trans, float* __restrict__ ws)
{
    __shared__ float attn_s[H*APAD];   // 24.2 KB
    __shared__ float og_s[288];
    const int n = blockIdx.x, tid = threadIdx.x;

    // load raw logits (row h at stride APAD)
    const float4* asrc = (const float4*)(ws + OFF_LOG + (size_t)n*H*N);
    for (int i = tid; i < H*(N/4); i += 512) {
        int h = i >> 7, q = i & 127;
        *(float4*)(attn_s + h*APAD + q*4) = asrc[h*128 + q];
    }
    __syncthreads();

    // softmax: one wave per row
    const int wave = tid >> 6, lane = tid & 63;
    for (int h = wave; h < H; h += 8) {
        float* row = attn_s + h*APAD;
        float v[8];
        float mx = -1e30f;
        #pragma unroll
        for (int j=0;j<8;j++){ v[j]=row[lane + j*64]; mx = fmaxf(mx, v[j]); }
        #pragma unroll
        for (int off=32; off>0; off>>=1) mx = fmaxf(mx, __shfl_xor(mx, off, 64));
        float sum = 0.f;
        #pragma unroll
        for (int j=0;j<8;j++){ v[j]=__expf(v[j]-mx); sum += v[j]; }
        #pragma unroll
        for (int off=32; off>0; off>>=1) sum += __shfl_xor(sum, off, 64);
        float inv = 1.f/sum;
        #pragma unroll
        for (int j=0;j<8;j++) row[lane + j*64] = v[j]*inv;
    }
    __syncthreads();

    if (wave < 6) {
        // phase B: pair_feat. h0 = wave, h1 = wave+6. cq = lane&31, sub = lane>>5.
        const int cq4 = (lane & 31) * 4;
        const int sub = lane >> 5;
        const float* zb = z + (size_t)n*N*CZ + cq4;
        const float4* arow0 = (const float4*)(attn_s + wave*APAD);
        const float4* arow1 = (const float4*)(attn_s + (wave+6)*APAD);
        float4 acc0 = {0.f,0.f,0.f,0.f}, acc1 = {0.f,0.f,0.f,0.f};
        for (int i = 0; i < N/8; i++) {
            int mq = 2*i + sub;            // interleaved odd/even 4-row chunks
            float4 a0 = arow0[mq];
            float4 a1 = arow1[mq];
            float4 z0 = *(const float4*)(zb + (size_t)(mq*4+0)*CZ);
            float4 z1 = *(const float4*)(zb + (size_t)(mq*4+1)*CZ);
            float4 z2 = *(const float4*)(zb + (size_t)(mq*4+2)*CZ);
            float4 z3 = *(const float4*)(zb + (size_t)(mq*4+3)*CZ);
            acc0.x += a0.x*z0.x + a0.y*z1.x + a0.z*z2.x + a0.w*z3.x;
            acc0.y += a0.x*z0.y + a0.y*z1.y + a0.z*z2.y + a0.w*z3.y;
            acc0.z += a0.x*z0.z + a0.y*z1.z + a0.z*z2.z + a0.w*z3.z;
            acc0.w += a0.x*z0.w + a0.y*z1.w + a0.z*z2.w + a0.w*z3.w;
            acc1.x += a1.x*z0.x + a1.y*z1.x + a1.z*z2.x + a1.w*z3.x;
            acc1.y += a1.x*z0.y + a1.y*z1.y + a1.z*z2.y + a1.w*z3.y;
            acc1.z += a1.x*z0.z + a1.y*z1.z + a1.z*z2.z + a1.w*z3.z;
            acc1.w += a1.x*z0.w + a1.y*z1.w + a1.z*z2.w + a1.w*z3.w;
        }
        // merge odd/even halves
        acc0.x += __shfl_xor(acc0.x, 32, 64); acc0.y += __shfl_xor(acc0.y, 32, 64);
        acc0.z += __shfl_xor(acc0.z, 32, 64); acc0.w += __shfl_xor(acc0.w, 32, 64);
        acc1.x += __shfl_xor(acc1.x, 32, 64); acc1.y += __shfl_xor(acc1.y, 32, 64);
        acc1.z += __shfl_xor(acc1.z, 32, 64); acc1.w += __shfl_xor(acc1.w, 32, 64);
        const int hst = (sub == 0) ? wave : wave + 6;
        float4 st = (sub == 0) ? acc0 : acc1;
        *(float4*)(ws + OFF_FEAT + (size_t)n*2112 + hst*176 + 48 + cq4) = st;
    } else {
        // phase A: out_scalar / out_pts global sums
        int t = tid - 384;               // 0..127, active col4<480
        int col4 = t * 4;
        if (col4 < 480) {
            const float* aptr; int astride, ah; bool isV;
            if (col4 < 192) { isV = true;  ah = col4 >> 4;        aptr = ws + OFF_V  + col4;       astride = 192; }
            else            { isV = false; ah = (col4-192) / 24;  aptr = ws + OFF_VG + (col4-192); astride = 288; }
            const float4* arow = (const float4*)(attn_s + ah*APAD);
            float4 acc = {0.f,0.f,0.f,0.f};
            for (int mq = 0; mq < N/4; mq++) {
                float4 a4 = arow[mq];
                const float* vp = aptr + (size_t)mq*4*astride;
                float4 v0 = *(const float4*)(vp);
                float4 v1 = *(const float4*)(vp + astride);
                float4 v2 = *(const float4*)(vp + 2*astride);
                float4 v3 = *(const float4*)(vp + 3*astride);
                acc.x += a4.x*v0.x + a4.y*v1.x + a4.z*v2.x + a4.w*v3.x;
                acc.y += a4.x*v0.y + a4.y*v1.y + a4.z*v2.y + a4.w*v3.y;
                acc.z += a4.x*v0.z + a4.y*v1.z + a4.z*v2.z + a4.w*v3.z;
                acc.w += a4.x*v0.w + a4.y*v1.w + a4.z*v2.w + a4.w*v3.w;
            }
            if (isV) *(float4*)(ws + OFF_FEAT + (size_t)n*2112 + ah*176 + (col4 & 15)) = acc;
            else     *(float4*)(og_s + (col4 - 192)) = acc;
        }
    }
    __syncthreads();

    // epilogue: rotate to local frame + norms
    if (tid < 96) {
        const int h = tid >> 3, p = tid & 7;
        float g0 = og_s[h*24 + p*3 + 0] - trans[n*3+0];
        float g1 = og_s[h*24 + p*3 + 1] - trans[n*3+1];
        float g2 = og_s[h*24 + p*3 + 2] - trans[n*3+2];
        const float* R = rot + n*9;
        float* fdst = ws + OFF_FEAT + (size_t)n*2112 + h*176;
        float nsq = 0.f;
        #pragma unroll
        for (int i=0;i<3;i++){
            float l = R[0*3+i]*g0 + R[1*3+i]*g1 + R[2*3+i]*g2;   // R^T
            fdst[16 + p*3 + i] = l;
            nsq += l*l;
        }
        fdst[40 + p] = sqrtf(nsq);
    }
}

// ---------------- Kernel 5a: init out with bias -----------------
__global__ __launch_bounds__(384) void k_bias(
    const float* __restrict__ bout, float* __restrict__ out)
{
    out[(size_t)blockIdx.x*CS + threadIdx.x] = bout[threadIdx.x];
}

// ---------------- Kernel 5b: output GEMM, K split 4 ways, atomicAdd ---------
__global__ __launch_bounds__(256) void k_out(
    const float* __restrict__ Wout, const float* __restrict__ ws,
    float* __restrict__ out)
{
    __shared__ float f_s[16*KSP];
    const int tid = threadIdx.x;
    const int n0  = blockIdx.y * 16;
    const int k0  = blockIdx.z * KSP;
    const int col = blockIdx.x * 64 + (tid & 15) * 4;
    const int nl  = tid >> 4;
    for (int i = tid; i < 16*KSP; i += 256) {
        int r = i / KSP, c = i - r*KSP;
        f_s[i] = ws[OFF_FEAT + (size_t)(n0 + r)*2112 + k0 + c];
    }
    __syncthreads();
    float4 acc = {0.f,0.f,0.f,0.f};
    const float* wp   = Wout + (size_t)k0*CS + col;
    const float* frow = f_s + nl*KSP;
    #pragma unroll 8
    for (int kk = 0; kk < KSP; kk++) {
        float4 w4 = *(const float4*)(wp + (size_t)kk*CS);
        float  fv = frow[kk];
        acc.x += fv*w4.x; acc.y += fv*w4.y; acc.z += fv*w4.z; acc.w += fv*w4.w;
    }
    float* o = out + (size_t)(n0+nl)*CS + col;
    atomicAdd(o+0, acc.x); atomicAdd(o+1, acc.y);
    atomicAdd(o+2, acc.z); atomicAdd(o+3, acc.w);
}

extern "C" void kernel_launch(void* const* d_in, const int* in_sizes, int n_in,
                              void* d_out, int out_size, void* d_ws, size_t ws_size,
                              hipStream_t stream) {
    const float* s     = (const float*)d_in[0];
    const float* z     = (const float*)d_in[1];
    const float* trans = (const float*)d_in[2];
    const float* rot   = (const float*)d_in[3];
    const float* Wq  = (const float*)d_in[5];  const float* bq  = (const float*)d_in[6];
    const float* Wk  = (const float*)d_in[7];  const float* bk  = (const float*)d_in[8];
    const float* Wv  = (const float*)d_in[9];  const float* bv  = (const float*)d_in[10];
    const float* Wqp = (const float*)d_in[11]; const float* bqp = (const float*)d_in[12];
    const float* Wkp = (const float*)d_in[13]; const float* bkp = (const float*)d_in[14];
    const float* Wvp = (const float*)d_in[15]; const float* bvp = (const float*)d_in[16];
    const float* Wb  = (const float*)d_in[17]; const float* bb  = (const float*)d_in[18];
    const float* dist_emb     = (const float*)d_in[19];
    const float* scale_logits = (const float*)d_in[20];
    const float* head_weights = (const float*)d_in[21];
    const float* Wout = (const float*)d_in[22]; const float* bout = (const float*)d_in[23];
    float* out = (float*)d_out;
    float* ws  = (float*)d_ws;

    k_proj<<<dim3(18, 32), 256, 0, stream>>>(s, Wq,bq, Wk,bk, Wv,bv, Wqp,bqp, Wkp,bkp, Wvp,bvp, ws);
    k_frames<<<N, 192, 0, stream>>>(rot, trans, ws);
    k_qkpt<<<dim3(8, 8, 12), 256, 0, stream>>>(head_weights, ws);
    k_zbias<<<dim3(2, 512), 256, 0, stream>>>(z, trans, Wb, bb, dist_emb, scale_logits, ws);
    k_attn<<<N, 512, 0, stream>>>(z, rot, trans, ws);
    k_bias<<<N, CS, 0, stream>>>(bout, out);
    k_out<<<dim3(6, 32, 4), 256, 0, stream>>>(Wout, ws, out);
}

// Round 7
// 414.924 us; speedup vs baseline: 1.1298x; 1.0802x over previous
//
#include <hip/hip_runtime.h>
#include <math.h>

#define N   512
#define CS  384
#define CZ  128
#define H   12
#define C   16
#define P   4
#define PV  8
#define NB  64
#define KSP 528   // K-slice for k_out (2112/4)
#define QKD 28    // 16 (q·k) + 12 (qg·kg) fused dot length
#define QPAD 68   // d-major LDS row stride (k_qkpt)
#define APAD 516  // attn LDS row stride

// workspace offsets (in floats)
#define OFF_Q    0         // 512*192
#define OFF_K    98304     // 512*192
#define OFF_V    196608    // 512*192
#define OFF_QP   294912    // 512*144
#define OFF_KP   368640    // 512*144
#define OFF_VP   442368    // 512*288
#define OFF_QG   589824    // 512*144
#define OFF_KG   663552    // 512*144
#define OFF_VG   737280    // 512*288
#define OFF_QSQ  884736    // 512*12
#define OFF_KSQ  890880    // 512*12
#define OFF_LOG  897024    // 512*12*512  (raw logits; softmax recomputed in LDS)
#define OFF_FEAT 4042752   // 512*2112

// ---------------- Kernel 1: all six projections (streamed GEMM) -----------------
__global__ __launch_bounds__(256) void k_proj(
    const float* __restrict__ s,
    const float* __restrict__ Wq,  const float* __restrict__ bq,
    const float* __restrict__ Wk,  const float* __restrict__ bk,
    const float* __restrict__ Wv,  const float* __restrict__ bv,
    const float* __restrict__ Wqp, const float* __restrict__ bqp,
    const float* __restrict__ Wkp, const float* __restrict__ bkp,
    const float* __restrict__ Wvp, const float* __restrict__ bvp,
    float* __restrict__ ws)
{
    __shared__ float s_s[16*388];
    const int tid = threadIdx.x;
    const int n0  = blockIdx.y * 16;
    const int gc  = blockIdx.x * 64 + (tid & 15) * 4;
    const int nl  = tid >> 4;
    for (int i = tid; i < 16*384; i += 256) {
        int r = i / 384, c = i - r*384;
        s_s[r*388 + c] = s[(n0 + r)*384 + c];
    }
    __syncthreads();
    const float* W; const float* b; float* dst; int width; int lc;
    if      (gc < 192) { W=Wq;  b=bq;  width=192; lc=gc;     dst=ws+OFF_Q;  }
    else if (gc < 384) { W=Wk;  b=bk;  width=192; lc=gc-192; dst=ws+OFF_K;  }
    else if (gc < 576) { W=Wv;  b=bv;  width=192; lc=gc-384; dst=ws+OFF_V;  }
    else if (gc < 720) { W=Wqp; b=bqp; width=144; lc=gc-576; dst=ws+OFF_QP; }
    else if (gc < 864) { W=Wkp; b=bkp; width=144; lc=gc-720; dst=ws+OFF_KP; }
    else               { W=Wvp; b=bvp; width=288; lc=gc-864; dst=ws+OFF_VP; }
    float4 acc = {0.f,0.f,0.f,0.f};
    const float* wp   = W + lc;
    const float* srow = s_s + nl*388;
    #pragma unroll 8
    for (int kk = 0; kk < 384; kk++) {
        float4 w4 = *(const float4*)(wp + (size_t)kk*width);
        float  sv = srow[kk];
        acc.x += sv*w4.x; acc.y += sv*w4.y; acc.z += sv*w4.z; acc.w += sv*w4.w;
    }
    float4 b4 = *(const float4*)(b + lc);
    acc.x += b4.x; acc.y += b4.y; acc.z += b4.z; acc.w += b4.w;
    *(float4*)(dst + (size_t)(n0+nl)*width + lc) = acc;
}

// ---------------- Kernel 2: global frames + q_sq/k_sq -----------------
__global__ __launch_bounds__(192) void k_frames(
    const float* __restrict__ rot, const float* __restrict__ trans,
    float* __restrict__ ws)
{
    int n = blockIdx.x, tid = threadIdx.x;
    __shared__ float R[9], T[3], qg_s[144], kg_s[144];
    if (tid < 9) R[tid] = rot[n*9 + tid];
    if (tid < 3) T[tid] = trans[n*3 + tid];
    __syncthreads();
    if (tid < 48) {
        const float* lp = ws + OFF_QP + n*144 + tid*3;
        float l0=lp[0], l1=lp[1], l2=lp[2];
        float* gp = ws + OFF_QG + n*144 + tid*3;
        for (int i=0;i<3;i++){ float g = R[i*3+0]*l0 + R[i*3+1]*l1 + R[i*3+2]*l2 + T[i]; gp[i]=g; qg_s[tid*3+i]=g; }
    } else if (tid < 96) {
        int u = tid-48;
        const float* lp = ws + OFF_KP + n*144 + u*3;
        float l0=lp[0], l1=lp[1], l2=lp[2];
        float* gp = ws + OFF_KG + n*144 + u*3;
        for (int i=0;i<3;i++){ float g = R[i*3+0]*l0 + R[i*3+1]*l1 + R[i*3+2]*l2 + T[i]; gp[i]=g; kg_s[u*3+i]=g; }
    } else {
        int u = tid-96;
        const float* lp = ws + OFF_VP + n*288 + u*3;
        float l0=lp[0], l1=lp[1], l2=lp[2];
        float* gp = ws + OFF_VG + n*288 + u*3;
        for (int i=0;i<3;i++){ float g = R[i*3+0]*l0 + R[i*3+1]*l1 + R[i*3+2]*l2 + T[i]; gp[i]=g; }
    }
    __syncthreads();
    if (tid < 12) {
        float a=0;
        for (int d=0; d<12; d++){ float x=qg_s[tid*12+d]; a+=x*x; }
        ws[OFF_QSQ + n*12 + tid]=a;
    } else if (tid < 24) {
        int h = tid-12; float a=0;
        for (int d=0; d<12; d++){ float x=kg_s[h*12+d]; a+=x*x; }
        ws[OFF_KSQ + n*12 + h]=a;
    }
}

// ---------------- Kernel 3a: qk + point logits, per-head 64x64 tiles ----------
__global__ __launch_bounds__(256) void k_qkpt(
    const float* __restrict__ head_weights, float* __restrict__ ws)
{
    __shared__ float qs[QKD*QPAD], ks[QKD*QPAD], qa[64], kb[64];
    const int tid = threadIdx.x;
    const int m0 = blockIdx.x * 64, n0 = blockIdx.y * 64, h = blockIdx.z;
    const float hw = head_weights[h];
    for (int idx = tid; idx < 64*16; idx += 256) {
        int r = idx >> 4, c = idx & 15;
        qs[c*QPAD + r] = ws[OFF_Q + (n0+r)*192 + h*16 + c] * 0.25f;
        ks[c*QPAD + r] = ws[OFF_K + (m0+r)*192 + h*16 + c];
    }
    for (int idx = tid; idx < 64*12; idx += 256) {
        int r = idx / 12, c = idx % 12;
        qs[(16+c)*QPAD + r] = ws[OFF_QG + (n0+r)*144 + h*12 + c] * hw;
        ks[(16+c)*QPAD + r] = ws[OFF_KG + (m0+r)*144 + h*12 + c];
    }
    for (int idx = tid; idx < 64; idx += 256) {
        qa[idx] = -0.5f * hw * ws[OFF_QSQ + (n0+idx)*12 + h];
        kb[idx] = -0.5f * hw * ws[OFF_KSQ + (m0+idx)*12 + h];
    }
    __syncthreads();
    const int tx = tid & 15, ty = tid >> 4;
    float acc[4][4] = {{0.f}};
    #pragma unroll 4
    for (int d = 0; d < QKD; d++) {
        float4 a = *(const float4*)(qs + d*QPAD + ty*4);
        float4 b = *(const float4*)(ks + d*QPAD + tx*4);
        const float* ap = &a.x; const float* bp = &b.x;
        #pragma unroll
        for (int i=0;i<4;i++)
            #pragma unroll
            for (int j=0;j<4;j++) acc[i][j] += ap[i]*bp[j];
    }
    #pragma unroll
    for (int i=0;i<4;i++) {
        float ai = qa[ty*4+i];
        float4 r;
        r.x = acc[i][0] + ai + kb[tx*4+0];
        r.y = acc[i][1] + ai + kb[tx*4+1];
        r.z = acc[i][2] + ai + kb[tx*4+2];
        r.w = acc[i][3] + ai + kb[tx*4+3];
        *(float4*)(ws + OFF_LOG + ((size_t)(n0+ty*4+i)*H + h)*N + m0 + tx*4) = r;
    }
}

// ---------------- Kernel 3b: += z@Wb + bb + dist_bias + multiscale -------------
__global__ __launch_bounds__(256) void k_zbias(
    const float* __restrict__ z, const float* __restrict__ trans,
    const float* __restrict__ Wb, const float* __restrict__ bb,
    const float* __restrict__ dist_emb, const float* __restrict__ scale_logits,
    float* __restrict__ ws)
{
    const int n = blockIdx.y;
    const int m = blockIdx.x * 256 + threadIdx.x;
    float dx = trans[n*3+0]-trans[m*3+0];
    float dy = trans[n*3+1]-trans[m*3+1];
    float dz = trans[n*3+2]-trans[m*3+2];
    float pd = sqrtf(dx*dx+dy*dy+dz*dz);
    int bin = (int)ceilf(2.f*pd) - 1;
    bin = bin < 0 ? 0 : (bin > NB-1 ? NB-1 : bin);
    const float4 de0 = *(const float4*)(dist_emb + bin*12);
    const float4 de1 = *(const float4*)(dist_emb + bin*12 + 4);
    const float4 de2 = *(const float4*)(dist_emb + bin*12 + 8);
    float de[12] = {de0.x,de0.y,de0.z,de0.w, de1.x,de1.y,de1.z,de1.w, de2.x,de2.y,de2.z,de2.w};
    float acc[12];
    #pragma unroll
    for (int h=0; h<12; h++) {
        float a = scale_logits[0*H+h], b = scale_logits[1*H+h], c = scale_logits[2*H+h];
        float mx = fmaxf(a, fmaxf(b,c));
        float ea=__expf(a-mx), eb=__expf(b-mx), ec=__expf(c-mx);
        float inv = 1.f/(ea+eb+ec);
        float msc = ec*inv;
        if (pd <= 5.f)       msc += ea*inv;
        else if (pd <= 15.f) msc += eb*inv;
        acc[h] = bb[h] + de[h] + msc;
    }
    const float* zp = z + ((size_t)n*N + m)*CZ;
    #pragma unroll 2
    for (int c4 = 0; c4 < CZ/4; c4++) {
        float4 z4 = *(const float4*)(zp + c4*4);
        const float* zv = &z4.x;
        #pragma unroll
        for (int j=0; j<4; j++)
            #pragma unroll
            for (int h=0; h<12; h++)
                acc[h] += zv[j] * Wb[(c4*4+j)*H + h];
    }
    float* lp = ws + OFF_LOG + (size_t)n*H*N + m;
    #pragma unroll
    for (int h=0; h<12; h++)
        lp[(size_t)h*N] += acc[h];
}

// ---------------- Kernel 4a: pair_feat = softmax(logits) @ z -------------------
// grid (2 c-halves, 512 n) x 256 thr. Softmax recomputed in LDS.
// thread = (c-quad cq 0..15, m-subset ms 0..15); 12 float4 accs (one per h);
// each z float4 load feeds 48 FMAs; z read once per block.
__global__ __launch_bounds__(256) void k_pairz(
    const float* __restrict__ z, float* __restrict__ ws)
{
    __shared__ float attn_s[H*APAD];     // 24.2 KB
    __shared__ float part[4*12*64];      // 12 KB wave partials
    const int ch = blockIdx.x, n = blockIdx.y;
    const int tid = threadIdx.x;
    const int lane = tid & 63, wave = tid >> 6;

    const float4* asrc = (const float4*)(ws + OFF_LOG + (size_t)n*H*N);
    for (int i = tid; i < H*(N/4); i += 256) {
        int h = i >> 7, q = i & 127;
        *(float4*)(attn_s + h*APAD + q*4) = asrc[h*128 + q];
    }
    __syncthreads();
    for (int h = wave; h < H; h += 4) {          // softmax, wave per row
        float* row = attn_s + h*APAD;
        float v[8]; float mx = -1e30f;
        #pragma unroll
        for (int j=0;j<8;j++){ v[j]=row[lane + j*64]; mx = fmaxf(mx, v[j]); }
        #pragma unroll
        for (int off=32; off>0; off>>=1) mx = fmaxf(mx, __shfl_xor(mx, off, 64));
        float sum = 0.f;
        #pragma unroll
        for (int j=0;j<8;j++){ v[j]=__expf(v[j]-mx); sum += v[j]; }
        #pragma unroll
        for (int off=32; off>0; off>>=1) sum += __shfl_xor(sum, off, 64);
        float inv = 1.f/sum;
        #pragma unroll
        for (int j=0;j<8;j++) row[lane + j*64] = v[j]*inv;
    }
    __syncthreads();

    const int cq = tid & 15;
    const int ms = tid >> 4;
    const float* zb = z + (size_t)n*N*CZ + ch*64 + cq*4;
    float4 acc[12];
    #pragma unroll
    for (int h=0; h<12; h++) acc[h] = make_float4(0.f,0.f,0.f,0.f);
    const int r0 = ms*32;
    #pragma unroll 2
    for (int rq = 0; rq < 8; rq++) {             // 4 rows per iter
        const int r = r0 + rq*4;
        float4 z0 = *(const float4*)(zb + (size_t)(r+0)*CZ);
        float4 z1 = *(const float4*)(zb + (size_t)(r+1)*CZ);
        float4 z2 = *(const float4*)(zb + (size_t)(r+2)*CZ);
        float4 z3 = *(const float4*)(zb + (size_t)(r+3)*CZ);
        #pragma unroll
        for (int h=0; h<12; h++) {
            float4 a4 = *(const float4*)(attn_s + h*APAD + r);
            acc[h].x += a4.x*z0.x + a4.y*z1.x + a4.z*z2.x + a4.w*z3.x;
            acc[h].y += a4.x*z0.y + a4.y*z1.y + a4.z*z2.y + a4.w*z3.y;
            acc[h].z += a4.x*z0.z + a4.y*z1.z + a4.z*z2.z + a4.w*z3.z;
            acc[h].w += a4.x*z0.w + a4.y*z1.w + a4.z*z2.w + a4.w*z3.w;
        }
    }
    // merge ms within wave: lanes +16 (ms+1) and +32 (ms+2)
    #pragma unroll
    for (int h=0; h<12; h++) {
        acc[h].x += __shfl_xor(acc[h].x, 16, 64); acc[h].y += __shfl_xor(acc[h].y, 16, 64);
        acc[h].z += __shfl_xor(acc[h].z, 16, 64); acc[h].w += __shfl_xor(acc[h].w, 16, 64);
        acc[h].x += __shfl_xor(acc[h].x, 32, 64); acc[h].y += __shfl_xor(acc[h].y, 32, 64);
        acc[h].z += __shfl_xor(acc[h].z, 32, 64); acc[h].w += __shfl_xor(acc[h].w, 32, 64);
    }
    if (lane < 16) {
        #pragma unroll
        for (int h=0; h<12; h++)
            *(float4*)(part + (wave*12 + h)*64 + lane*4) = acc[h];
    }
    __syncthreads();
    if (tid < 192) {                             // final 4-way reduce + store
        const int h = tid >> 4, c4 = tid & 15;
        float4 s = *(const float4*)(part + (0*12 + h)*64 + c4*4);
        #pragma unroll
        for (int w=1; w<4; w++) {
            float4 p = *(const float4*)(part + (w*12 + h)*64 + c4*4);
            s.x += p.x; s.y += p.y; s.z += p.z; s.w += p.w;
        }
        *(float4*)(ws + OFF_FEAT + (size_t)n*2112 + h*176 + 48 + ch*64 + c4*4) = s;
    }
}

// ---------------- Kernel 4b: attn@{V,VG} + rotate + norms ----------------------
// 512 blocks x 256 thr. Softmax recomputed in LDS. thread = (col4 of 120, m-half).
__global__ __launch_bounds__(256) void k_attnA(
    const float* __restrict__ rot, const float* __restrict__ trans,
    float* __restrict__ ws)
{
    __shared__ float attn_s[H*APAD];     // 24.2 KB
    __shared__ float part[240*4];        // 3.75 KB
    __shared__ float og_s[288];
    const int n = blockIdx.x, tid = threadIdx.x;
    const int lane = tid & 63, wave = tid >> 6;

    const float4* asrc = (const float4*)(ws + OFF_LOG + (size_t)n*H*N);
    for (int i = tid; i < H*(N/4); i += 256) {
        int h = i >> 7, q = i & 127;
        *(float4*)(attn_s + h*APAD + q*4) = asrc[h*128 + q];
    }
    __syncthreads();
    for (int h = wave; h < H; h += 4) {          // softmax, wave per row
        float* row = attn_s + h*APAD;
        float v[8]; float mx = -1e30f;
        #pragma unroll
        for (int j=0;j<8;j++){ v[j]=row[lane + j*64]; mx = fmaxf(mx, v[j]); }
        #pragma unroll
        for (int off=32; off>0; off>>=1) mx = fmaxf(mx, __shfl_xor(mx, off, 64));
        float sum = 0.f;
        #pragma unroll
        for (int j=0;j<8;j++){ v[j]=__expf(v[j]-mx); sum += v[j]; }
        #pragma unroll
        for (int off=32; off>0; off>>=1) sum += __shfl_xor(sum, off, 64);
        float inv = 1.f/sum;
        #pragma unroll
        for (int j=0;j<8;j++) row[lane + j*64] = v[j]*inv;
    }
    __syncthreads();

    if (tid < 240) {
        const int col4 = (tid % 120) * 4;
        const int msA  = tid / 120;              // 0 or 1 -> rows msA*256..+255
        const float* aptr; int astride, ah;
        if (col4 < 192) { ah = col4 >> 4;        aptr = ws + OFF_V  + col4;       astride = 192; }
        else            { ah = (col4-192) / 24;  aptr = ws + OFF_VG + (col4-192); astride = 288; }
        const float4* arow = (const float4*)(attn_s + ah*APAD);
        float4 acc = {0.f,0.f,0.f,0.f};
        #pragma unroll 2
        for (int mq = msA*64; mq < msA*64 + 64; mq++) {
            float4 a4 = arow[mq];
            const float* vp = aptr + (size_t)mq*4*astride;
            float4 v0 = *(const float4*)(vp);
            float4 v1 = *(const float4*)(vp + astride);
            float4 v2 = *(const float4*)(vp + 2*astride);
            float4 v3 = *(const float4*)(vp + 3*astride);
            acc.x += a4.x*v0.x + a4.y*v1.x + a4.z*v2.x + a4.w*v3.x;
            acc.y += a4.x*v0.y + a4.y*v1.y + a4.z*v2.y + a4.w*v3.y;
            acc.z += a4.x*v0.z + a4.y*v1.z + a4.z*v2.z + a4.w*v3.z;
            acc.w += a4.x*v0.w + a4.y*v1.w + a4.z*v2.w + a4.w*v3.w;
        }
        *(float4*)(part + tid*4) = acc;
    }
    __syncthreads();
    if (tid < 120) {
        const int col4 = tid * 4;
        float4 a = *(const float4*)(part + tid*4);
        float4 b = *(const float4*)(part + (tid+120)*4);
        a.x += b.x; a.y += b.y; a.z += b.z; a.w += b.w;
        if (col4 < 192) {
            const int ah = col4 >> 4;
            *(float4*)(ws + OFF_FEAT + (size_t)n*2112 + ah*176 + (col4 & 15)) = a;
        } else {
            *(float4*)(og_s + (col4 - 192)) = a;
        }
    }
    __syncthreads();
    if (tid < 96) {                              // rotate to local frame + norms
        const int h = tid >> 3, p = tid & 7;
        float g0 = og_s[h*24 + p*3 + 0] - trans[n*3+0];
        float g1 = og_s[h*24 + p*3 + 1] - trans[n*3+1];
        float g2 = og_s[h*24 + p*3 + 2] - trans[n*3+2];
        const float* R = rot + n*9;
        float* fdst = ws + OFF_FEAT + (size_t)n*2112 + h*176;
        float nsq = 0.f;
        #pragma unroll
        for (int i=0;i<3;i++){
            float l = R[0*3+i]*g0 + R[1*3+i]*g1 + R[2*3+i]*g2;   // R^T
            fdst[16 + p*3 + i] = l;
            nsq += l*l;
        }
        fdst[40 + p] = sqrtf(nsq);
    }
}

// ---------------- Kernel 5a: init out with bias -----------------
__global__ __launch_bounds__(384) void k_bias(
    const float* __restrict__ bout, float* __restrict__ out)
{
    out[(size_t)blockIdx.x*CS + threadIdx.x] = bout[threadIdx.x];
}

// ---------------- Kernel 5b: output GEMM, K split 4 ways, atomicAdd ---------
__global__ __launch_bounds__(256) void k_out(
    const float* __restrict__ Wout, const float* __restrict__ ws,
    float* __restrict__ out)
{
    __shared__ float f_s[16*KSP];
    const int tid = threadIdx.x;
    const int n0  = blockIdx.y * 16;
    const int k0  = blockIdx.z * KSP;
    const int col = blockIdx.x * 64 + (tid & 15) * 4;
    const int nl  = tid >> 4;
    for (int i = tid; i < 16*KSP; i += 256) {
        int r = i / KSP, c = i - r*KSP;
        f_s[i] = ws[OFF_FEAT + (size_t)(n0 + r)*2112 + k0 + c];
    }
    __syncthreads();
    float4 acc = {0.f,0.f,0.f,0.f};
    const float* wp   = Wout + (size_t)k0*CS + col;
    const float* frow = f_s + nl*KSP;
    #pragma unroll 8
    for (int kk = 0; kk < KSP; kk++) {
        float4 w4 = *(const float4*)(wp + (size_t)kk*CS);
        float  fv = frow[kk];
        acc.x += fv*w4.x; acc.y += fv*w4.y; acc.z += fv*w4.z; acc.w += fv*w4.w;
    }
    float* o = out + (size_t)(n0+nl)*CS + col;
    atomicAdd(o+0, acc.x); atomicAdd(o+1, acc.y);
    atomicAdd(o+2, acc.z); atomicAdd(o+3, acc.w);
}

extern "C" void kernel_launch(void* const* d_in, const int* in_sizes, int n_in,
                              void* d_out, int out_size, void* d_ws, size_t ws_size,
                              hipStream_t stream) {
    const float* s     = (const float*)d_in[0];
    const float* z     = (const float*)d_in[1];
    const float* trans = (const float*)d_in[2];
    const float* rot   = (const float*)d_in[3];
    const float* Wq  = (const float*)d_in[5];  const float* bq  = (const float*)d_in[6];
    const float* Wk  = (const float*)d_in[7];  const float* bk  = (const float*)d_in[8];
    const float* Wv  = (const float*)d_in[9];  const float* bv  = (const float*)d_in[10];
    const float* Wqp = (const float*)d_in[11]; const float* bqp = (const float*)d_in[12];
    const float* Wkp = (const float*)d_in[13]; const float* bkp = (const float*)d_in[14];
    const float* Wvp = (const float*)d_in[15]; const float* bvp = (const float*)d_in[16];
    const float* Wb  = (const float*)d_in[17]; const float* bb  = (const float*)d_in[18];
    const float* dist_emb     = (const float*)d_in[19];
    const float* scale_logits = (const float*)d_in[20];
    const float* head_weights = (const float*)d_in[21];
    const float* Wout = (const float*)d_in[22]; const float* bout = (const float*)d_in[23];
    float* out = (float*)d_out;
    float* ws  = (float*)d_ws;

    k_proj<<<dim3(18, 32), 256, 0, stream>>>(s, Wq,bq, Wk,bk, Wv,bv, Wqp,bqp, Wkp,bkp, Wvp,bvp, ws);
    k_frames<<<N, 192, 0, stream>>>(rot, trans, ws);
    k_qkpt<<<dim3(8, 8, 12), 256, 0, stream>>>(head_weights, ws);
    k_zbias<<<dim3(2, 512), 256, 0, stream>>>(z, trans, Wb, bb, dist_emb, scale_logits, ws);
    k_pairz<<<dim3(2, 512), 256, 0, stream>>>(z, ws);
    k_attnA<<<N, 256, 0, stream>>>(rot, trans, ws);
    k_bias<<<N, CS, 0, stream>>>(bout, out);
    k_out<<<dim3(6, 32, 4), 256, 0, stream>>>(Wout, ws, out);
}